// Round 5
// baseline (666.337 us; speedup 1.0000x reference)
//
#include <hip/hip_runtime.h>

#define N_NODES 5000
#define N_EDGES 160000
#define HID 64
#define BATCH 512
#define CSTRIDE 96          // per-node neighbor cap: deg ~ Poisson(32), P(>96) ~ e^-60
#define G 1024              // 4 blocks/CU x 256 CU: co-resident by __launch_bounds__(256,4)
#define NT (G * 256)        // 262144 threads
#define NWAVES (G * 4)      // 4096 waves
#define NODE_ITERS 2        // ceil(5000 / 4096), uniform trip count

// ws layout (bytes):
//   0        cnt      5000 i32   (zeroed by prologue dispatch)
//   20000    compact  5000*96 i32 = 1,920,000
//   1940000  h1       5000*64 f32 = 1,280,000
//   3220000  h_part   5000*64 f32 = 1,280,000
//   4500000  t_part   512*64 f32  =   131,072
//   4631072  Wl1T(256) Wr1T(256) Wl2T(4096) Wr2T(4096) Wc1hT(4096) f32
//   4682272  bar      96 i32     (3 barrier counters, 128B apart; zeroed by prologue)

// ---------- dispatch 0: zero cnt + barrier counters ----------
__global__ __launch_bounds__(256) void zero_kernel(int* __restrict__ cnt,
                                                   int* __restrict__ bar) {
    int i = blockIdx.x * 256 + threadIdx.x;
    if (i < N_NODES) cnt[i] = 0;
    if (blockIdx.x == 0 && threadIdx.x < 96) bar[threadIdx.x] = 0;
}

// Grid barrier, capture-safe. Arrival: one device-scope RMW per block. Poll: relaxed
// AGENT atomic LOAD (no ownership transfer — r4's RMW-poll cost ~80us/barrier and
// 120 MB of fabric traffic). Co-residency of all G blocks guaranteed by
// __launch_bounds__(256,4) => <=128 VGPR => 4 blocks/CU x 256 CU = 1024 = G.
__device__ inline void gbar(int* __restrict__ bar, int idx) {
    __syncthreads();
    if (threadIdx.x == 0) {
        __threadfence();                                   // release prior stores
        atomicAdd(&bar[idx * 32], 1);                      // device-scope arrival
        while (__hip_atomic_load(&bar[idx * 32], __ATOMIC_RELAXED,
                                 __HIP_MEMORY_SCOPE_AGENT) < G)
            __builtin_amdgcn_s_sleep(8);                   // ~512 cyc between polls
        __threadfence();                                   // acquire
    }
    __syncthreads();
}

// ---------- dispatch 1: whole pipeline, 4 phases, 3 internal grid barriers ----------
__global__ __launch_bounds__(256, 4) void fused_kernel(
        const float* __restrict__ x, const int* __restrict__ ei,
        const float* __restrict__ task_feat,
        const float* __restrict__ Wl1, const float* __restrict__ bl1,
        const float* __restrict__ Wr1,
        const float* __restrict__ Wl2, const float* __restrict__ bl2,
        const float* __restrict__ Wr2,
        const float* __restrict__ Wt1, const float* __restrict__ bt1,
        const float* __restrict__ Wt2, const float* __restrict__ bt2,
        const float* __restrict__ Wc1, const float* __restrict__ bc1,
        const float* __restrict__ Wc2, const float* __restrict__ bc2,
        int* __restrict__ cnt, int* __restrict__ compact,
        float* __restrict__ h1, float* __restrict__ h_part,
        float* __restrict__ t_part,
        float* __restrict__ Wl1T, float* __restrict__ Wr1T,
        float* __restrict__ Wl2T, float* __restrict__ Wr2T,
        float* __restrict__ Wc1hT, int* __restrict__ bar,
        float* __restrict__ out) {
    int tid  = threadIdx.x;
    int blk  = blockIdx.x;
    int gid  = blk * 256 + tid;
    int lane = tid & 63, grp = tid >> 6;
    int w    = blk * 4 + grp;          // global wave id, 0..4095

    __shared__ union SM {
        struct { float s1[4][64]; float s2[4][64]; } t;                  // phase A
        struct { float m[4][64]; float h[4][64]; float h2[4][64]; } l2;  // phase D
    } sm;

    // ---- phase A: edge build + weight transposes + task MLP (all independent) ----
    if (gid < N_EDGES) {                               // NT > N_EDGES: single shot
        int src = ei[gid];
        int dst = ei[N_EDGES + gid];
        int q = atomicAdd(&cnt[dst], 1);               // device-scope, mean 32 hits/ctr
        if (q < CSTRIDE) compact[dst * CSTRIDE + q] = src;
    }
    if (gid < 4096) {
        Wl2T[gid] = Wl2[(gid & 63) * 64 + (gid >> 6)];
    } else if (gid < 8192) {
        int idx = gid - 4096;
        Wr2T[idx] = Wr2[(idx & 63) * 64 + (idx >> 6)];
    } else if (gid < 12288) {
        int idx = gid - 8192;
        Wc1hT[idx] = Wc1[(idx & 63) * 128 + (idx >> 6)];
    } else if (gid < 12544) {
        int idx = gid - 12288;
        Wl1T[idx] = Wl1[(idx & 63) * 4 + (idx >> 6)];
        Wr1T[idx] = Wr1[(idx & 63) * 4 + (idx >> 6)];
    }
    if (blk < BATCH / 4) {             // blocks 0..127: task MLP, 4 batch rows per block
        int b = blk * 4 + grp, h = lane;
        float4 tf = ((const float4*)task_feat)[b];
        float4 w1 = ((const float4*)Wt1)[h];
        float v = bt1[h] + tf.x * w1.x + tf.y * w1.y + tf.z * w1.z + tf.w * w1.w;
        sm.t.s1[grp][h] = fmaxf(v, 0.f);
        __syncthreads();               // block-uniform branch
        const float4* w2r = (const float4*)(Wt2 + h * 64);
        const float4* s1v = (const float4*)sm.t.s1[grp];
        float v2 = bt2[h];
#pragma unroll
        for (int q = 0; q < 16; q++) {
            float4 ww = w2r[q]; float4 ss = s1v[q];
            v2 += ss.x * ww.x + ss.y * ww.y + ss.z * ww.z + ss.w * ww.w;
        }
        sm.t.s2[grp][h] = v2;          // no relu on 2nd task layer
        __syncthreads();
        const float4* wcr = (const float4*)(Wc1 + h * 128 + 64);
        const float4* s2v = (const float4*)sm.t.s2[grp];
        float p = bc1[h];
#pragma unroll
        for (int q = 0; q < 16; q++) {
            float4 ww = wcr[q]; float4 ss = s2v[q];
            p += ss.x * ww.x + ss.y * ww.y + ss.z * ww.z + ss.w * ww.w;
        }
        t_part[b * 64 + h] = p;
    }
    gbar(bar, 0);

    // ---- phase C: layer 1 (4->64), one node per wave ----
    for (int it = 0; it < NODE_ITERS; ++it) {
        int n = w + it * NWAVES;       // wave-uniform
        if (n < N_NODES) {
            int d = min(cnt[n], CSTRIDE);
            const int* row = compact + n * CSTRIDE;
            float4 xs = make_float4(0.f, 0.f, 0.f, 0.f);
            if (lane < d) {
                float4 xv = ((const float4*)x)[row[lane]];
                xs.x += xv.x; xs.y += xv.y; xs.z += xv.z; xs.w += xv.w;
            }
            if (lane + 64 < d) {
                float4 xv = ((const float4*)x)[row[lane + 64]];
                xs.x += xv.x; xs.y += xv.y; xs.z += xv.z; xs.w += xv.w;
            }
#pragma unroll
            for (int off = 1; off < 64; off <<= 1) {
                xs.x += __shfl_xor(xs.x, off);
                xs.y += __shfl_xor(xs.y, off);
                xs.z += __shfl_xor(xs.z, off);
                xs.w += __shfl_xor(xs.w, off);
            }
            float inv = 1.f / fmaxf((float)d, 1.f);
            float m0 = xs.x * inv, m1 = xs.y * inv, m2 = xs.z * inv, m3 = xs.w * inv;
            float4 xn = ((const float4*)x)[n];
            float v = bl1[lane]
                    + m0 * Wl1T[lane] + m1 * Wl1T[64 + lane]
                    + m2 * Wl1T[128 + lane] + m3 * Wl1T[192 + lane]
                    + xn.x * Wr1T[lane] + xn.y * Wr1T[64 + lane]
                    + xn.z * Wr1T[128 + lane] + xn.w * Wr1T[192 + lane];
            h1[n * 64 + lane] = fmaxf(v, 0.f);
        }
    }
    gbar(bar, 1);

    // ---- phase D: layer 2 (64->64) + h_part; uniform trips, unconditional barriers ----
    for (int it = 0; it < NODE_ITERS; ++it) {
        int n = w + it * NWAVES;
        bool valid = n < N_NODES;
        int nn = valid ? n : 0;
        int h = lane;
        int d = valid ? min(cnt[nn], CSTRIDE) : 0;
        const int* bucket = compact + nn * CSTRIDE;
        float a0 = 0.f, a1 = 0.f, a2 = 0.f, a3 = 0.f;
        int j = 0;
        for (; j + 4 <= d; j += 4) {
            int e0 = bucket[j], e1 = bucket[j + 1], e2 = bucket[j + 2], e3 = bucket[j + 3];
            a0 += h1[e0 * 64 + h];
            a1 += h1[e1 * 64 + h];
            a2 += h1[e2 * 64 + h];
            a3 += h1[e3 * 64 + h];
        }
        for (; j < d; j++) a0 += h1[bucket[j] * 64 + h];
        float m = (a0 + a1 + a2 + a3) / fmaxf((float)d, 1.f);

        sm.l2.m[grp][h] = m;
        sm.l2.h[grp][h] = h1[nn * 64 + h];
        __syncthreads();
        float v = bl2[h];
#pragma unroll
        for (int k = 0; k < 64; k++)
            v += sm.l2.m[grp][k] * Wl2T[k * 64 + h] + sm.l2.h[grp][k] * Wr2T[k * 64 + h];
        sm.l2.h2[grp][h] = fmaxf(v, 0.f);
        __syncthreads();
        float p = 0.f;
#pragma unroll
        for (int k = 0; k < 64; k++) p += sm.l2.h2[grp][k] * Wc1hT[k * 64 + h];
        if (valid) h_part[n * 64 + h] = p;
        __syncthreads();               // protect LDS rows before next iteration
    }
    gbar(bar, 2);

    // ---- phase E: scores; 1280 pieces = 20 node-tiles x 64 batch-tiles ----
    float b2 = bc2[0];
    for (int p = blk; p < 20 * 64; p += G) {
        int bt = p / 20, ntile = p - bt * 20;
        int n = ntile * 256 + tid;
        bool valid = n < N_NODES;
        int nn = valid ? n : (N_NODES - 1);
        float hr[64];
        const float4* hp = (const float4*)(h_part + nn * 64);
#pragma unroll
        for (int i = 0; i < 16; i++) {
            float4 v = hp[i];
            hr[4 * i + 0] = v.x; hr[4 * i + 1] = v.y;
            hr[4 * i + 2] = v.z; hr[4 * i + 3] = v.w;
        }
        int b0 = bt * 8;
        for (int bb = 0; bb < 8; bb++) {
            const float* tp = t_part + (b0 + bb) * 64;   // wave-uniform -> scalar loads
            float acc0 = 0.f, acc1 = 0.f, acc2 = 0.f, acc3 = 0.f;
#pragma unroll
            for (int h = 0; h < 64; h += 4) {
                acc0 = fmaf(fmaxf(hr[h + 0] + tp[h + 0], 0.f), Wc2[h + 0], acc0);
                acc1 = fmaf(fmaxf(hr[h + 1] + tp[h + 1], 0.f), Wc2[h + 1], acc1);
                acc2 = fmaf(fmaxf(hr[h + 2] + tp[h + 2], 0.f), Wc2[h + 2], acc2);
                acc3 = fmaf(fmaxf(hr[h + 3] + tp[h + 3], 0.f), Wc2[h + 3], acc3);
            }
            if (valid)
                out[(b0 + bb) * N_NODES + n] = (acc0 + acc1) + (acc2 + acc3) + b2;
        }
    }
}

// ---------- launch: 2 plain dispatches (capture-safe) ----------
extern "C" void kernel_launch(void* const* d_in, const int* in_sizes, int n_in,
                              void* d_out, int out_size, void* d_ws, size_t ws_size,
                              hipStream_t stream) {
    const float* x    = (const float*)d_in[0];
    const int*   ei   = (const int*)d_in[1];
    const float* task = (const float*)d_in[2];
    const float* Wl1  = (const float*)d_in[3];
    const float* bl1  = (const float*)d_in[4];
    const float* Wr1  = (const float*)d_in[5];
    const float* Wl2  = (const float*)d_in[6];
    const float* bl2  = (const float*)d_in[7];
    const float* Wr2  = (const float*)d_in[8];
    const float* Wt1  = (const float*)d_in[9];
    const float* bt1  = (const float*)d_in[10];
    const float* Wt2  = (const float*)d_in[11];
    const float* bt2  = (const float*)d_in[12];
    const float* Wc1  = (const float*)d_in[13];
    const float* bc1  = (const float*)d_in[14];
    const float* Wc2  = (const float*)d_in[15];
    const float* bc2  = (const float*)d_in[16];
    float* out = (float*)d_out;

    char* ws = (char*)d_ws;
    int*   cnt     = (int*)(ws + 0);
    int*   compact = (int*)(ws + 20000);
    float* h1      = (float*)(ws + 1940000);
    float* h_part  = (float*)(ws + 3220000);
    float* t_part  = (float*)(ws + 4500000);
    float* Wl1T  = (float*)(ws + 4631072);
    float* Wr1T  = (float*)(ws + 4632096);
    float* Wl2T  = (float*)(ws + 4633120);
    float* Wr2T  = (float*)(ws + 4649504);
    float* Wc1hT = (float*)(ws + 4665888);
    int*   bar   = (int*)(ws + 4682272);

    zero_kernel<<<(N_NODES + 255) / 256, 256, 0, stream>>>(cnt, bar);
    fused_kernel<<<G, 256, 0, stream>>>(
        x, ei, task, Wl1, bl1, Wr1, Wl2, bl2, Wr2,
        Wt1, bt1, Wt2, bt2, Wc1, bc1, Wc2, bc2,
        cnt, compact, h1, h_part, t_part,
        Wl1T, Wr1T, Wl2T, Wr2T, Wc1hT, bar, out);
}

// Round 6
// 150.604 us; speedup vs baseline: 4.4244x; 4.4244x over previous
//
#include <hip/hip_runtime.h>

#define N_NODES 5000
#define N_EDGES 160000
#define HID 64
#define BATCH 512
#define CSTRIDE 96   // per-node neighbor cap: deg ~ Poisson(32), P(>96) ~ e^-60, never binds

// ws layout (bytes):
//   0        cnt      5000 i32                  (zeroed by prep)
//   20000    compact  5000*96 i32 = 1,920,000
//   1940000  h1       5000*64 f32 = 1,280,000
//   3220000  h_part   5000*64 f32 = 1,280,000
//   4500000  t_part   512*64 f32  =   131,072
//   4631072  Wl1T(256) Wr1T(256) Wl2T(4096) Wr2T(4096) Wc1hT(4096) f32

// ---------- dispatch 0: prep = zero cnt + weight transposes + task MLP ----------
// All edge-independent work lives here so build is a uniform pure scatter.
__global__ __launch_bounds__(256) void prep_kernel(
        const float* __restrict__ task_feat,
        const float* __restrict__ Wt1, const float* __restrict__ bt1,
        const float* __restrict__ Wt2, const float* __restrict__ bt2,
        const float* __restrict__ Wc1, const float* __restrict__ bc1,
        const float* __restrict__ Wl1, const float* __restrict__ Wr1,
        const float* __restrict__ Wl2, const float* __restrict__ Wr2,
        int* __restrict__ cnt, float* __restrict__ t_part,
        float* __restrict__ Wl1T, float* __restrict__ Wr1T,
        float* __restrict__ Wl2T, float* __restrict__ Wr2T,
        float* __restrict__ Wc1hT) {
    int tid = threadIdx.x;
    int blk = blockIdx.x;
    __shared__ float s1[4][64];
    __shared__ float s2[4][64];

    if (blk < 20) {                        // zero cnt (20*256 = 5120 >= 5000)
        int i = blk * 256 + tid;
        if (i < N_NODES) cnt[i] = 0;
    } else if (blk < 24) {
        int w = blk - 20;
        if (w == 0) {
            for (int idx = tid; idx < 4096; idx += 256)
                Wl2T[idx] = Wl2[(idx & 63) * 64 + (idx >> 6)];
        } else if (w == 1) {
            for (int idx = tid; idx < 4096; idx += 256)
                Wr2T[idx] = Wr2[(idx & 63) * 64 + (idx >> 6)];
        } else if (w == 2) {
            for (int idx = tid; idx < 4096; idx += 256)
                Wc1hT[idx] = Wc1[(idx & 63) * 128 + (idx >> 6)];
        } else {
            Wl1T[tid] = Wl1[(tid & 63) * 4 + (tid >> 6)];
            Wr1T[tid] = Wr1[(tid & 63) * 4 + (tid >> 6)];
        }
    } else {
        // task MLP + t-half of classifier: 4 batch rows per block (blocks 24..151)
        int grp = tid >> 6, h = tid & 63;
        int b = (blk - 24) * 4 + grp;
        float4 tf = ((const float4*)task_feat)[b];
        float4 w1 = ((const float4*)Wt1)[h];
        float v = bt1[h] + tf.x * w1.x + tf.y * w1.y + tf.z * w1.z + tf.w * w1.w;
        s1[grp][h] = fmaxf(v, 0.f);
        __syncthreads();                   // block-uniform branch
        const float4* w2r = (const float4*)(Wt2 + h * 64);
        const float4* s1v = (const float4*)s1[grp];
        float v2 = bt2[h];
#pragma unroll
        for (int q = 0; q < 16; q++) {
            float4 w = w2r[q]; float4 ss = s1v[q];
            v2 += ss.x * w.x + ss.y * w.y + ss.z * w.z + ss.w * w.w;
        }
        s2[grp][h] = v2;                   // no relu on 2nd task layer
        __syncthreads();
        const float4* wcr = (const float4*)(Wc1 + h * 128 + 64);
        const float4* s2v = (const float4*)s2[grp];
        float p = bc1[h];
#pragma unroll
        for (int q = 0; q < 16; q++) {
            float4 w = wcr[q]; float4 ss = s2v[q];
            p += ss.x * w.x + ss.y * w.y + ss.z * w.z + ss.w * w.w;
        }
        t_part[b * 64 + h] = p;
    }
}

// ---------- dispatch 1: edge build — uniform pure scatter, 1 edge/thread ----------
__global__ __launch_bounds__(256) void build_kernel(
        const int* __restrict__ ei, int* __restrict__ cnt, int* __restrict__ compact) {
    int e = blockIdx.x * 256 + threadIdx.x;        // 625*256 == 160000 exactly
    int src = ei[e];                               // coalesced
    int dst = ei[N_EDGES + e];                     // coalesced
    int q = atomicAdd(&cnt[dst], 1);               // device-scope L2 atomic, mean 32/ctr
    if (q < CSTRIDE) compact[dst * CSTRIDE + q] = src;
}

// ---------- dispatch 2: layer 1 (4->64), wave per node, coalesced list read ----------
__global__ __launch_bounds__(256) void layer1_kernel(
        const float* __restrict__ x, const int* __restrict__ cnt,
        const int* __restrict__ compact,
        const float* __restrict__ Wl1T, const float* __restrict__ bl1,
        const float* __restrict__ Wr1T, float* __restrict__ h1) {
    int lane = threadIdx.x & 63, grp = threadIdx.x >> 6;
    int n = blockIdx.x * 4 + grp;
    int d = min(cnt[n], CSTRIDE);               // wave-uniform
    const int* row = compact + n * CSTRIDE;
    float4 xs = make_float4(0.f, 0.f, 0.f, 0.f);
    if (lane < d) {                             // coalesced 64-wide list read
        float4 xv = ((const float4*)x)[row[lane]];
        xs.x += xv.x; xs.y += xv.y; xs.z += xv.z; xs.w += xv.w;
    }
    if (lane + 64 < d) {                        // d>64 is ~1e-7/node
        float4 xv = ((const float4*)x)[row[lane + 64]];
        xs.x += xv.x; xs.y += xv.y; xs.z += xv.z; xs.w += xv.w;
    }
#pragma unroll
    for (int off = 1; off < 64; off <<= 1) {    // butterfly reduce float4
        xs.x += __shfl_xor(xs.x, off);
        xs.y += __shfl_xor(xs.y, off);
        xs.z += __shfl_xor(xs.z, off);
        xs.w += __shfl_xor(xs.w, off);
    }
    float inv = 1.f / fmaxf((float)d, 1.f);
    float m0 = xs.x * inv, m1 = xs.y * inv, m2 = xs.z * inv, m3 = xs.w * inv;
    float4 xn = ((const float4*)x)[n];
    float v = bl1[lane]
            + m0 * Wl1T[lane] + m1 * Wl1T[64 + lane]
            + m2 * Wl1T[128 + lane] + m3 * Wl1T[192 + lane]
            + xn.x * Wr1T[lane] + xn.y * Wr1T[64 + lane]
            + xn.z * Wr1T[128 + lane] + xn.w * Wr1T[192 + lane];
    h1[n * 64 + lane] = fmaxf(v, 0.f);
}

// ---------- dispatch 3: layer 2 (64->64) fused with h_part = h2 @ Wc1[:,:64].T ----------
// 8-wide gather unroll; both 64-deep FMA chains split into 4 partial accumulators
// (dependency depth 128 -> 32 and 64 -> 16).
__global__ __launch_bounds__(256) void layer2_kernel(
        const float* __restrict__ h1, const int* __restrict__ cnt,
        const int* __restrict__ compact,
        const float* __restrict__ Wl2T, const float* __restrict__ bl2,
        const float* __restrict__ Wr2T, const float* __restrict__ Wc1hT,
        float* __restrict__ h_part) {
    int h = threadIdx.x & 63, grp = threadIdx.x >> 6;
    int n = blockIdx.x * 4 + grp;
    int d = min(cnt[n], CSTRIDE);
    const int* bucket = compact + n * CSTRIDE;
    float a0 = 0.f, a1 = 0.f, a2 = 0.f, a3 = 0.f;
    float a4 = 0.f, a5 = 0.f, a6 = 0.f, a7 = 0.f;
    int j = 0;
    for (; j + 8 <= d; j += 8) {                // 8 independent gathers in flight
        int e0 = bucket[j],     e1 = bucket[j + 1], e2 = bucket[j + 2], e3 = bucket[j + 3];
        int e4 = bucket[j + 4], e5 = bucket[j + 5], e6 = bucket[j + 6], e7 = bucket[j + 7];
        a0 += h1[e0 * 64 + h]; a1 += h1[e1 * 64 + h];
        a2 += h1[e2 * 64 + h]; a3 += h1[e3 * 64 + h];
        a4 += h1[e4 * 64 + h]; a5 += h1[e5 * 64 + h];
        a6 += h1[e6 * 64 + h]; a7 += h1[e7 * 64 + h];
    }
    for (; j + 4 <= d; j += 4) {
        int e0 = bucket[j], e1 = bucket[j + 1], e2 = bucket[j + 2], e3 = bucket[j + 3];
        a0 += h1[e0 * 64 + h]; a1 += h1[e1 * 64 + h];
        a2 += h1[e2 * 64 + h]; a3 += h1[e3 * 64 + h];
    }
    for (; j < d; j++) a0 += h1[bucket[j] * 64 + h];
    float m = (((a0 + a1) + (a2 + a3)) + ((a4 + a5) + (a6 + a7))) / fmaxf((float)d, 1.f);

    __shared__ float shm[4][64], shh[4][64], shh2[4][64];
    shm[grp][h] = m;
    shh[grp][h] = h1[n * 64 + h];
    __syncthreads();
    float v0 = 0.f, v1 = 0.f, v2 = 0.f, v3 = 0.f;
#pragma unroll
    for (int k = 0; k < 64; k += 4) {
        v0 += shm[grp][k    ] * Wl2T[(k    ) * 64 + h] + shh[grp][k    ] * Wr2T[(k    ) * 64 + h];
        v1 += shm[grp][k + 1] * Wl2T[(k + 1) * 64 + h] + shh[grp][k + 1] * Wr2T[(k + 1) * 64 + h];
        v2 += shm[grp][k + 2] * Wl2T[(k + 2) * 64 + h] + shh[grp][k + 2] * Wr2T[(k + 2) * 64 + h];
        v3 += shm[grp][k + 3] * Wl2T[(k + 3) * 64 + h] + shh[grp][k + 3] * Wr2T[(k + 3) * 64 + h];
    }
    float v = bl2[h] + ((v0 + v1) + (v2 + v3));
    shh2[grp][h] = fmaxf(v, 0.f);
    __syncthreads();
    float p0 = 0.f, p1 = 0.f, p2 = 0.f, p3 = 0.f;
#pragma unroll
    for (int k = 0; k < 64; k += 4) {
        p0 += shh2[grp][k    ] * Wc1hT[(k    ) * 64 + h];
        p1 += shh2[grp][k + 1] * Wc1hT[(k + 1) * 64 + h];
        p2 += shh2[grp][k + 2] * Wc1hT[(k + 2) * 64 + h];
        p3 += shh2[grp][k + 3] * Wc1hT[(k + 3) * 64 + h];
    }
    h_part[n * 64 + h] = (p0 + p1) + (p2 + p3);
}

// ---------- dispatch 4: scores[b,n] = sum_h relu(hp[n,h]+tp[b,h])*Wc2[h] + bc2 ----------
__global__ __launch_bounds__(256) void scores_kernel(
        const float* __restrict__ h_part, const float* __restrict__ t_part,
        const float* __restrict__ Wc2, const float* __restrict__ bc2,
        float* __restrict__ out) {
    int tid = threadIdx.x;
    int n = blockIdx.x * 256 + tid;
    bool valid = n < N_NODES;
    int nn = valid ? n : (N_NODES - 1);
    float hr[64];
    const float4* hp = (const float4*)(h_part + nn * 64);
#pragma unroll
    for (int i = 0; i < 16; i++) {
        float4 v = hp[i];
        hr[4 * i + 0] = v.x; hr[4 * i + 1] = v.y;
        hr[4 * i + 2] = v.z; hr[4 * i + 3] = v.w;
    }
    float b2 = bc2[0];
    int b0 = blockIdx.y * 8;
    for (int bb = 0; bb < 8; bb++) {
        const float* tp = t_part + (b0 + bb) * 64;   // wave-uniform -> scalar loads
        float acc0 = 0.f, acc1 = 0.f, acc2 = 0.f, acc3 = 0.f;
#pragma unroll
        for (int h = 0; h < 64; h += 4) {
            acc0 = fmaf(fmaxf(hr[h + 0] + tp[h + 0], 0.f), Wc2[h + 0], acc0);
            acc1 = fmaf(fmaxf(hr[h + 1] + tp[h + 1], 0.f), Wc2[h + 1], acc1);
            acc2 = fmaf(fmaxf(hr[h + 2] + tp[h + 2], 0.f), Wc2[h + 2], acc2);
            acc3 = fmaf(fmaxf(hr[h + 3] + tp[h + 3], 0.f), Wc2[h + 3], acc3);
        }
        if (valid)
            out[(b0 + bb) * N_NODES + n] = (acc0 + acc1) + (acc2 + acc3) + b2;
    }
}

// ---------- launch ----------
extern "C" void kernel_launch(void* const* d_in, const int* in_sizes, int n_in,
                              void* d_out, int out_size, void* d_ws, size_t ws_size,
                              hipStream_t stream) {
    const float* x    = (const float*)d_in[0];
    const int*   ei   = (const int*)d_in[1];
    const float* task = (const float*)d_in[2];
    const float* Wl1  = (const float*)d_in[3];
    const float* bl1  = (const float*)d_in[4];
    const float* Wr1  = (const float*)d_in[5];
    const float* Wl2  = (const float*)d_in[6];
    const float* bl2  = (const float*)d_in[7];
    const float* Wr2  = (const float*)d_in[8];
    const float* Wt1  = (const float*)d_in[9];
    const float* bt1  = (const float*)d_in[10];
    const float* Wt2  = (const float*)d_in[11];
    const float* bt2  = (const float*)d_in[12];
    const float* Wc1  = (const float*)d_in[13];
    const float* bc1  = (const float*)d_in[14];
    const float* Wc2  = (const float*)d_in[15];
    const float* bc2  = (const float*)d_in[16];
    float* out = (float*)d_out;

    char* ws = (char*)d_ws;
    int*   cnt     = (int*)(ws + 0);
    int*   compact = (int*)(ws + 20000);
    float* h1      = (float*)(ws + 1940000);
    float* h_part  = (float*)(ws + 3220000);
    float* t_part  = (float*)(ws + 4500000);
    float* Wl1T  = (float*)(ws + 4631072);
    float* Wr1T  = (float*)(ws + 4632096);
    float* Wl2T  = (float*)(ws + 4633120);
    float* Wr2T  = (float*)(ws + 4649504);
    float* Wc1hT = (float*)(ws + 4665888);

    prep_kernel<<<20 + 4 + BATCH / 4, 256, 0, stream>>>(
        task, Wt1, bt1, Wt2, bt2, Wc1, bc1, Wl1, Wr1, Wl2, Wr2,
        cnt, t_part, Wl1T, Wr1T, Wl2T, Wr2T, Wc1hT);
    build_kernel<<<N_EDGES / 256, 256, 0, stream>>>(ei, cnt, compact);
    layer1_kernel<<<N_NODES / 4, 256, 0, stream>>>(x, cnt, compact, Wl1T, bl1, Wr1T, h1);
    layer2_kernel<<<N_NODES / 4, 256, 0, stream>>>(h1, cnt, compact, Wl2T, bl2, Wr2T,
                                                   Wc1hT, h_part);
    scores_kernel<<<dim3(20, 64), 256, 0, stream>>>(h_part, t_part, Wc2, bc2, out);
}